// Round 7
// baseline (377.168 us; speedup 1.0000x reference)
//
#include <hip/hip_runtime.h>

using u16 = unsigned short;
using u32 = unsigned int;
typedef __attribute__((ext_vector_type(8))) __bf16 bf16x8;
typedef __attribute__((ext_vector_type(8))) u16 u16x8;
typedef __attribute__((ext_vector_type(4))) float f32x4;

#define DEVI __device__ __forceinline__

constexpr int BN_ = 128;              // batch
constexpr int NN  = 1024;             // graph nodes
constexpr int CH  = 66;               // IN_DIM + HID
constexpr int HD  = 64;               // HID
constexpr int RR  = BN_ * CH;         // 8448 rows
constexpr long RN = (long)RR * NN;    // elements per part
constexpr int KTRUE = 330, KPAD = 352;
constexpr long M2 = (long)NN * NN;

DEVI float bf2f(u16 u) { u32 i = ((u32)u) << 16; float f; __builtin_memcpy(&f, &i, 4); return f; }
DEVI u16 f2bf(float f) { u32 i; __builtin_memcpy(&i, &f, 4); i += 0x7fffu + ((i >> 16) & 1u); return (u16)(i >> 16); }

DEVI void gl_lds16(const void* g, void* l) {
  __builtin_amdgcn_global_load_lds((const __attribute__((address_space(1))) u32*)g,
                                   (__attribute__((address_space(3))) u32*)l, 16, 0, 0);
}

// ---- main GEMM:  Y[r,col] = sum_n X[r,n]*A[col,n] ----
// Round-7 change: 4 LDS buffers, prefetch distance 3 (was 3 bufs / distance 2).
// Ledger (per wave, 4 loads/STAGE): prologue stages t=0,1,2 -> 12 outstanding,
// vmcnt(8) drains tile0. Step t: STAGE(t+3) -> outstanding {t+1,t+2,t+3}=12,
// vmcnt(8) drains t+1. Tail: t=29 vmcnt(4), t=30 vmcnt(0).
// Frag/index math byte-identical to the validated round-4/5/6 kernel.
template<int TMZ>
__global__ __launch_bounds__(256, 2)
void gemm_db(const u16* __restrict__ Xb, long xzs,
             const u16* __restrict__ Ab, long azs,
             u16* __restrict__ Yb, long ozs)
{
  __shared__ u16 L[4 * 8192];   // 64 KB: 4 bufs x (X 8KB + B 8KB)
  const int bid = blockIdx.x;
  const int wg  = (bid & 7) * (gridDim.x >> 3) + (bid >> 3);
  const int z   = wg / TMZ;
  const int rem = wg - z * TMZ;
  const int tm  = rem >> 3, tn = rem & 7;

  const u16* X = Xb + (long)z * xzs;
  const u16* A = Ab + (long)z * azs;
  u16*       Y = Yb + (long)z * ozs;
  const int tid = threadIdx.x, wv = tid >> 6, ln = tid & 63;

  const int r0  = wv * 16 + (ln >> 2);
  const int kch = (((ln & 3) ^ ((r0 >> 1) & 3))) * 8;
  const u16* gX = X + (long)(tm * 128 + r0) * NN + kch;
  const u16* gA = A + (long)(tn * 128 + r0) * NN + kch;
  const int lofs = wv * 512;

  const int frow = ln & 15;
  const int fk   = ((ln >> 4) ^ ((ln >> 1) & 3)) * 8;
  const int wr = wv >> 1, wc = wv & 1;

  f32x4 acc[4][4] = {};

#define STAGE(T, BUF) do {                                  \
    u16* bx_ = &L[(BUF) * 8192 + lofs];                     \
    u16* bb_ = &L[(BUF) * 8192 + 4096 + lofs];              \
    const int k0_ = (T) * 32;                               \
    gl_lds16(gX + k0_,           bx_);                      \
    gl_lds16(gX + k0_ + 64 * NN, bx_ + 2048);               \
    gl_lds16(gA + k0_,           bb_);                      \
    gl_lds16(gA + k0_ + 64 * NN, bb_ + 2048);               \
  } while (0)

  STAGE(0, 0);
  STAGE(1, 1);
  STAGE(2, 2);
  asm volatile("s_waitcnt vmcnt(8)" ::: "memory");
  __builtin_amdgcn_s_barrier();
  __builtin_amdgcn_sched_barrier(0);

  int cur = 0;
  for (int t = 0; t < 32; ++t) {
    if (t + 3 < 32) STAGE(t + 3, (cur + 3) & 3);   // buf last read at t-1
    const u16* bx = &L[cur * 8192];
    const u16* bb = bx + 4096;
    bf16x8 af[4], bfv[4];
#pragma unroll
    for (int m = 0; m < 4; m++) af[m]  = *(const bf16x8*)&bx[(wr * 64 + m * 16 + frow) * 32 + fk];
#pragma unroll
    for (int n = 0; n < 4; n++) bfv[n] = *(const bf16x8*)&bb[(wc * 64 + n * 16 + frow) * 32 + fk];
#pragma unroll
    for (int m = 0; m < 4; m++)
#pragma unroll
      for (int n = 0; n < 4; n++)
        acc[m][n] = __builtin_amdgcn_mfma_f32_16x16x32_bf16(af[m], bfv[n], acc[m][n], 0, 0, 0);
    if (t < 31) {
      if (t + 3 < 32)   asm volatile("s_waitcnt vmcnt(8)" ::: "memory");
      else if (t == 29) asm volatile("s_waitcnt vmcnt(4)" ::: "memory");
      else              asm volatile("s_waitcnt vmcnt(0)" ::: "memory");
      __builtin_amdgcn_s_barrier();
      __builtin_amdgcn_sched_barrier(0);
    }
    cur = (cur + 1) & 3;
  }
#undef STAGE

  // C/D layout: col = lane&15, row = (lane>>4)*4 + q   [validated]
  const int colb = tn * 128 + wc * 64 + frow;
  const int rowb = tm * 128 + wr * 64 + (ln >> 4) * 4;
#pragma unroll
  for (int m = 0; m < 4; m++)
#pragma unroll
    for (int n = 0; n < 4; n++) {
      const int col = colb + n * 16;
#pragma unroll
      for (int q = 0; q < 4; q++) {
        const long r = rowb + m * 16 + q;
        Y[r * NN + col] = f2bf(acc[m][n][q]);
      }
    }
}

// ---- B2 = 2*A*A - I on 64x64 tiles (512 blocks, kills the 128-block bubble) ----
// Same staging swizzle / frag math as the validated kernel, scaled to 64-row
// tiles (one gl_lds16 per matrix per K-step). 3 bufs, 2 loads/STAGE ->
// prologue vmcnt(2); in-loop vmcnt(2); tail vmcnt(0).
__global__ __launch_bounds__(256, 2)
void gemm_sq64(const u16* __restrict__ Xb, long xzs,
               const u16* __restrict__ Ab, long azs,
               u16* __restrict__ Yb, long ozs)
{
  __shared__ u16 L[3 * 4096];   // 24 KB: 3 bufs x (X 4KB + B 4KB)
  const int bid = blockIdx.x;
  const int wg  = (bid & 7) * 64 + (bid >> 3);    // grid 512 = 8 x 64
  const int z   = wg >> 8;
  const int rem = wg & 255;
  const int tm  = rem >> 4, tn = rem & 15;

  const u16* X = Xb + (long)z * xzs;
  const u16* A = Ab + (long)z * azs;
  u16*       Y = Yb + (long)z * ozs;
  const int tid = threadIdx.x, wv = tid >> 6, ln = tid & 63;

  const int r0  = wv * 16 + (ln >> 2);            // 0..63
  const int kch = (((ln & 3) ^ ((r0 >> 1) & 3))) * 8;
  const u16* gX = X + (long)(tm * 64 + r0) * NN + kch;
  const u16* gA = A + (long)(tn * 64 + r0) * NN + kch;
  const int lofs = wv * 512;

  const int frow = ln & 15;
  const int fk   = ((ln >> 4) ^ ((ln >> 1) & 3)) * 8;
  const int wr = wv >> 1, wc = wv & 1;

  f32x4 acc[2][2] = {};

#define STAGE2(T, BUF) do {                                 \
    const int k0_ = (T) * 32;                               \
    gl_lds16(gX + k0_, &L[(BUF) * 4096 + lofs]);            \
    gl_lds16(gA + k0_, &L[(BUF) * 4096 + 2048 + lofs]);     \
  } while (0)

  STAGE2(0, 0);
  STAGE2(1, 1);
  asm volatile("s_waitcnt vmcnt(2)" ::: "memory");
  __builtin_amdgcn_s_barrier();
  __builtin_amdgcn_sched_barrier(0);

  int cur = 0;
  for (int t = 0; t < 32; ++t) {
    const int nx = (cur >= 1) ? cur - 1 : cur + 2;
    if (t + 2 < 32) STAGE2(t + 2, nx);
    const u16* bx = &L[cur * 4096];
    const u16* bb = bx + 2048;
    bf16x8 af[2], bfv[2];
#pragma unroll
    for (int m = 0; m < 2; m++) af[m]  = *(const bf16x8*)&bx[(wr * 32 + m * 16 + frow) * 32 + fk];
#pragma unroll
    for (int n = 0; n < 2; n++) bfv[n] = *(const bf16x8*)&bb[(wc * 32 + n * 16 + frow) * 32 + fk];
#pragma unroll
    for (int m = 0; m < 2; m++)
#pragma unroll
      for (int n = 0; n < 2; n++)
        acc[m][n] = __builtin_amdgcn_mfma_f32_16x16x32_bf16(af[m], bfv[n], acc[m][n], 0, 0, 0);
    if (t < 31) {
      if (t + 2 < 32) asm volatile("s_waitcnt vmcnt(2)" ::: "memory");
      else            asm volatile("s_waitcnt vmcnt(0)" ::: "memory");
      __builtin_amdgcn_s_barrier();
      __builtin_amdgcn_sched_barrier(0);
    }
    cur = (cur >= 2) ? 0 : cur + 1;
  }
#undef STAGE2

  const int colb = tn * 64 + wc * 32 + frow;
  const int rowb = tm * 64 + wr * 32 + (ln >> 4) * 4;
#pragma unroll
  for (int m = 0; m < 2; m++)
#pragma unroll
    for (int n = 0; n < 2; n++) {
      const int col = colb + n * 16;
#pragma unroll
      for (int q = 0; q < 4; q++) {
        const int r = rowb + m * 16 + q;
        const float v = 2.0f * acc[m][n][q] - (r == col ? 1.0f : 0.0f);
        Y[(long)r * NN + col] = f2bf(v);
      }
    }
}

// ---- fused transpose + projection (VALIDATED round 5/6 — unchanged) ----
template<int O, bool FINAL>
__global__ __launch_bounds__(512)
void proj_f(const u16* __restrict__ part0, const u16* __restrict__ Yb,
            const u16* __restrict__ W, const float* __restrict__ bias,
            const float* __restrict__ hx, const u16* __restrict__ zpad,
            u16* __restrict__ xcrow, float* __restrict__ ubuf,
            float* __restrict__ outp)
{
  __shared__ u16 LB[23040];   // 64 rows x 720B (704 data + 16 pad)
  __shared__ u16 LA[5632];    // 176c x 32n c-major, 11 x 1KB chunks
  const int b = blockIdx.y, n0 = blockIdx.x * 64;
  const int tid = threadIdx.x, wv = tid >> 6, ln = tid & 63;

  const int of  = (O == 128) ? wv : (wv >> 1);
  const int nfb = (O == 128) ? 0  : 2 * (wv & 1);
  constexpr int NF = (O == 128) ? 4 : 2;
  const int frow = ln & 15, klane = ln >> 4;

  const u16* wb = W + (long)(of * 16 + frow) * KPAD + klane * 8;
  bf16x8 wf[11];
#pragma unroll
  for (int t = 0; t < 11; ++t) wf[t] = *(const bf16x8*)(wb + t * 32);

  for (int hf = 0; hf < 2; ++hf)
#pragma unroll 1
    for (int ch = 0; ch < 2; ++ch) {
#pragma unroll
      for (int ii = 0; ii < 2; ++ii) {
        const int i = ii * 8 + wv;
        if (i < 11) {
          const int c = ch * 176 + 16 * i + (ln >> 2);
          const u16* src;
          if (c < KTRUE) {
            const int p = c / 66, f = c - 66 * p;
            const u16* base = (p == 0) ? part0 : (Yb + (long)(p - 1) * RN);
            src = base + (long)(b * CH + f) * NN + n0 + hf * 32 + (ln & 3) * 8;
          } else {
            src = zpad;
          }
          gl_lds16(src, (char*)LA + i * 1024);
        }
      }
      __syncthreads();
#pragma unroll
      for (int it = 0; it < 2; ++it) {
        const int q = it * 512 + tid;
        if (q < 704) {
          const int n = q & 31, cch = q >> 5;
          u16x8 v;
#pragma unroll
          for (int j = 0; j < 8; ++j) v[j] = LA[(cch * 8 + j) * 32 + n];
          *(u16x8*)((char*)LB + (hf * 32 + n) * 720 + ch * 352 + cch * 16) = v;
        }
      }
      __syncthreads();
    }

  f32x4 acc[NF] = {};
#pragma unroll
  for (int t = 0; t < 11; ++t) {
#pragma unroll
    for (int j = 0; j < NF; ++j) {
      const int nf = nfb + j;
      const bf16x8 bt = *(const bf16x8*)((char*)LB + (nf * 16 + frow) * 720 + t * 64 + klane * 16);
      acc[j] = __builtin_amdgcn_mfma_f32_16x16x32_bf16(wf[t], bt, acc[j], 0, 0, 0);
    }
  }

  const int orow = klane * 4;
#pragma unroll
  for (int j = 0; j < NF; ++j) {
    const int nf = nfb + j;
    const int ncol = n0 + nf * 16 + frow;
#pragma unroll
    for (int q = 0; q < 4; ++q) {
      const int o = of * 16 + orow + q;
      const float pre = acc[j][q] + bias[o];
      if (!FINAL) {
        const float sg = 1.0f / (1.0f + __expf(-pre));
        if (o < HD) {
          const float hv = hx[(long)(b * HD + o) * NN + ncol];
          xcrow[(long)(b * CH + 2 + o) * NN + ncol] = f2bf(sg * hv);
        } else {
          ubuf[(long)(b * HD + (o - HD)) * NN + ncol] = sg;
        }
      } else {
        const float e  = __expf(2.0f * pre);
        const float cc = 1.0f - 2.0f / (e + 1.0f);
        const long oi = (long)(b * HD + o) * NN + ncol;
        const float u = ubuf[oi];
        outp[oi] = u * hx[oi] + (1.0f - u) * cc;
      }
    }
  }
}

// ---- build X = bf16([inputs; hx]) rows; also seed XC's input channels ----
__global__ void build_x(const float* __restrict__ inp, const float* __restrict__ hx,
                        u16* __restrict__ X, u16* __restrict__ XC)
{
  const int row = blockIdx.x;
  const int b = row / 66, f = row - b * 66;
  const int n0 = threadIdx.x * 4;
  const float* s = (f < 2) ? (inp + (long)(b * 2 + f) * NN) : (hx + (long)(b * HD + f - 2) * NN);
  const float4 v = *(const float4*)(s + n0);
  ushort4 o;
  o.x = f2bf(v.x); o.y = f2bf(v.y); o.z = f2bf(v.z); o.w = f2bf(v.w);
  *(ushort4*)&X[(long)row * NN + n0] = o;
  if (f < 2) *(ushort4*)&XC[(long)row * NN + n0] = o;
}

// ---- A (f32, [m][n]) -> AT (bf16, [n][m])  (VALIDATED round 2/6) ----
__global__ void xposeA(const float* __restrict__ A0, const float* __restrict__ A1,
                       u16* __restrict__ AT)
{
  __shared__ float Ls[64][65];
  const int z = blockIdx.z;
  const float* A = z ? A1 : A0;
  u16* out = AT + (long)z * M2;
  const int m0 = blockIdx.y * 64, n0 = blockIdx.x * 64;
  const int t = threadIdx.x;
  const int rr = t >> 6, cc = t & 63;
#pragma unroll
  for (int i = 0; i < 16; i++)
    Ls[i * 4 + rr][cc] = A[(long)(m0 + i * 4 + rr) * NN + n0 + cc];
  __syncthreads();
  const int n = t >> 2, mc = (t & 3) * 16;
  u16 tmp[16];
#pragma unroll
  for (int k = 0; k < 16; k++) tmp[k] = f2bf(Ls[mc + k][n]);
  u16* dst = &out[(long)(n0 + n) * NN + m0 + mc];
  *(ushort4*)(dst + 0)  = *(ushort4*)&tmp[0];
  *(ushort4*)(dst + 4)  = *(ushort4*)&tmp[4];
  *(ushort4*)(dst + 8)  = *(ushort4*)&tmp[8];
  *(ushort4*)(dst + 12) = *(ushort4*)&tmp[12];
}

// ---- convert A0->slot0, A1->slot2 of Abf2; pad+convert W's (VALIDATED) ----
__global__ void prep(const float* __restrict__ A0, const float* __restrict__ A1,
                     const float* __restrict__ Wru, const float* __restrict__ WC,
                     u16* __restrict__ Abf2, u16* __restrict__ Wrub, u16* __restrict__ WCb)
{
  const int gid = blockIdx.x * 256 + threadIdx.x;
  if (gid < 524288) {
    const bool sec = gid >= 262144;
    const float* s = sec ? (A1 + (long)(gid - 262144) * 4) : (A0 + (long)gid * 4);
    u16* d = sec ? (Abf2 + 2 * M2 + (long)(gid - 262144) * 4) : (Abf2 + (long)gid * 4);
    const float4 v = *(const float4*)s;
    ushort4 o; o.x = f2bf(v.x); o.y = f2bf(v.y); o.z = f2bf(v.z); o.w = f2bf(v.w);
    *(ushort4*)d = o;
  } else if (gid < 524288 + 128 * KPAD) {
    const int g = gid - 524288;
    const int o = g / KPAD, c = g - o * KPAD;
    Wrub[g] = f2bf(c < KTRUE ? Wru[o * KTRUE + c] : 0.0f);
  } else if (gid < 524288 + 128 * KPAD + 64 * KPAD) {
    const int g = gid - 524288 - 128 * KPAD;
    const int o = g / KPAD, c = g - o * KPAD;
    WCb[g] = f2bf(c < KTRUE ? WC[o * KTRUE + c] : 0.0f);
  }
}

extern "C" void kernel_launch(void* const* d_in, const int* in_sizes, int n_in,
                              void* d_out, int out_size, void* d_ws, size_t ws_size,
                              hipStream_t stream)
{
  const float* inp = (const float*)d_in[0];
  const float* hx  = (const float*)d_in[1];
  const float* A0  = (const float*)d_in[2];
  const float* A1  = (const float*)d_in[3];
  const float* Wru = (const float*)d_in[4];
  const float* bru = (const float*)d_in[5];
  const float* WC  = (const float*)d_in[6];
  const float* bC  = (const float*)d_in[7];
  float* out = (float*)d_out;

  char* ws = (char*)d_ws;
  u16* Abf2 = (u16*)(ws);                 //  8,388,608 B  [A0, B2_0, A1, B2_1]
  u16* ATbf = (u16*)(ws + 8388608);       //  4,194,304 B  [A0^T, A1^T]
  u16* Wrub = (u16*)(ws + 12582912);      //     90,112 B  (128x352)
  u16* WCb  = (u16*)(ws + 12673024);      //     45,056 B  (64x352)
  u16* zpad = (u16*)(ws + 12718080);      //        256 B  zeros
  u16* X    = (u16*)(ws + 12718336);      // 17,301,504 B
  u16* XC   = (u16*)(ws + 30019840);      // 17,301,504 B
  u16* Yb   = (u16*)(ws + 47321344);      // 69,206,016 B  (4 parts) -> 116,527,360 B
  float* ub = out;                        // u-gate parked in d_out between proj1/proj2

  hipMemsetAsync(zpad, 0, 256, stream);
  prep<<<2312, 256, 0, stream>>>(A0, A1, Wru, WC, Abf2, Wrub, WCb);
  xposeA<<<dim3(16, 16, 2), 256, 0, stream>>>(A0, A1, ATbf);
  build_x<<<RR, 256, 0, stream>>>(inp, hx, X, XC);

  // B2_z = 2*A_z*A_z - I  into Abf2 slots 1,3  (64x64 tiles, 512 blocks)
  gemm_sq64<<<512, 256, 0, stream>>>(Abf2, 2 * M2, ATbf, M2, Abf2 + M2, 2 * M2);

  const dim3 gx(16, BN_);
  // round 1: one z=4 dispatch -> parts [Y1_0, Y2_0, Y1_1, Y2_1]
  gemm_db<528><<<2112, 256, 0, stream>>>(X, 0, Abf2, M2, Yb, RN);
  proj_f<128, false><<<gx, 512, 0, stream>>>(X, Yb, Wrub, bru, hx, zpad, XC, ub, nullptr);

  // round 2
  gemm_db<528><<<2112, 256, 0, stream>>>(XC, 0, Abf2, M2, Yb, RN);
  proj_f<64, true><<<gx, 512, 0, stream>>>(XC, Yb, WCb, bC, hx, zpad, nullptr, ub, out);
}